// Round 1
// baseline (265.638 us; speedup 1.0000x reference)
//
#include <hip/hip_runtime.h>
#include <hip/hip_bf16.h>

// pos[b][f][i][j] = row_embed[Z(i,j)][f],  Z = max(|32-j| + |32-i| - 1, 0)
// b=32, F=512, h=w=64. Output fp32, 256 MiB -> write-BW bound.
//
// Thread t in [0, F*h*w/4): f = t/1024, i = (t%1024)/16, j4 = (t%16)*4.
// Gather 4 table values once, store float4 to all 32 batch copies.

#define NUM_POS_FEATS 512
#define LEN_EMB 64
#define H 64
#define W 64
#define B 32

__global__ __launch_bounds__(256) void pe_kernel(const float* __restrict__ row_embed,
                                                 float* __restrict__ out) {
    const int t = blockIdx.x * blockDim.x + threadIdx.x;   // 0 .. 524287
    const int f   = t >> 10;          // / (h*w/4) = /1024
    const int rem = t & 1023;
    const int i   = rem >> 4;         // / (w/4) = /16
    const int j4  = (rem & 15) << 2;  // quad start column

    const int di = abs(32 - i);

    float vals[4];
#pragma unroll
    for (int k = 0; k < 4; ++k) {
        const int j = j4 + k;
        int z = di + abs(32 - j) - 1;
        z = z < 0 ? 0 : z;
        vals[k] = row_embed[z * NUM_POS_FEATS + f];
    }
    const float4 v = make_float4(vals[0], vals[1], vals[2], vals[3]);

    const size_t base    = (size_t)f * (H * W) + (size_t)i * W + (size_t)j4;
    const size_t bstride = (size_t)NUM_POS_FEATS * H * W;   // 2,097,152 floats

#pragma unroll
    for (int b = 0; b < B; ++b) {
        *reinterpret_cast<float4*>(out + base + (size_t)b * bstride) = v;
    }
}

extern "C" void kernel_launch(void* const* d_in, const int* in_sizes, int n_in,
                              void* d_out, int out_size, void* d_ws, size_t ws_size,
                              hipStream_t stream) {
    // d_in[0] = x (32,3,64,64) fp32 — unused (shape only)
    // d_in[1] = row_embed (64,512) fp32
    const float* row_embed = (const float*)d_in[1];
    float* out = (float*)d_out;

    const int total_quads = NUM_POS_FEATS * H * W / 4;   // 524288
    const int block = 256;
    const int grid = total_quads / block;                // 2048
    pe_kernel<<<grid, block, 0, stream>>>(row_embed, out);
}

// Round 2
// 256.618 us; speedup vs baseline: 1.0352x; 1.0352x over previous
//
#include <hip/hip_runtime.h>
#include <hip/hip_bf16.h>

// pos[b][f][i][j] = row_embed[Z(i,j)][f],  Z = max(|32-j| + |32-i| - 1, 0)
// b=32, F=512, h=w=64. Output fp32, 256 MiB -> pure write-BW bound.
//
// R1 lesson: the 32-way batch fan-out (stores 8 MiB apart per wave) broke the
// linear write stream and landed at ~1 TB/s vs memset's 6.6 TB/s.
// R2 structure: one block per (b,f) image. Block writes its 16 KB contiguously
// (consecutive blocks -> consecutive memory, memset-shaped stream). The 64
// distinct table values for feature f are staged in LDS once per block.

#define NUM_POS_FEATS 512
#define H 64
#define W 64
#define B 32

__global__ __launch_bounds__(256) void pe_kernel(const float* __restrict__ row_embed,
                                                 float* __restrict__ out) {
    __shared__ float col[64];   // row_embed[z][f] for z in [0,64)

    const int bf  = blockIdx.x;        // b*512 + f, 0..16383
    const int f   = bf & (NUM_POS_FEATS - 1);
    const int tid = threadIdx.x;

    if (tid < 64) {
        col[tid] = row_embed[tid * NUM_POS_FEATS + f];
    }
    __syncthreads();

    // This block's image: 64*64 = 4096 floats = 1024 float4 quads.
    float4* o = reinterpret_cast<float4*>(out + (size_t)bf * (H * W));

#pragma unroll
    for (int k = 0; k < 4; ++k) {
        const int idx = k * 256 + tid;        // quad index 0..1023
        const int i   = idx >> 4;             // row
        const int j4  = (idx & 15) << 2;      // quad start column
        const int di  = abs(32 - i);

        float4 v;
        {
            int z = di + abs(32 - (j4 + 0)) - 1; v.x = col[z < 0 ? 0 : z];
        }
        {
            int z = di + abs(32 - (j4 + 1)) - 1; v.y = col[z < 0 ? 0 : z];
        }
        {
            int z = di + abs(32 - (j4 + 2)) - 1; v.z = col[z < 0 ? 0 : z];
        }
        {
            int z = di + abs(32 - (j4 + 3)) - 1; v.w = col[z < 0 ? 0 : z];
        }
        o[idx] = v;
    }
}

extern "C" void kernel_launch(void* const* d_in, const int* in_sizes, int n_in,
                              void* d_out, int out_size, void* d_ws, size_t ws_size,
                              hipStream_t stream) {
    // d_in[0] = x (32,3,64,64) fp32 — unused (shape only)
    // d_in[1] = row_embed (64,512) fp32
    const float* row_embed = (const float*)d_in[1];
    float* out = (float*)d_out;

    const int grid = B * NUM_POS_FEATS;   // 16384 blocks, one per (b,f) image
    pe_kernel<<<grid, 256, 0, stream>>>(row_embed, out);
}